// Round 4
// baseline (579.185 us; speedup 1.0000x reference)
//
#include <hip/hip_runtime.h>
#include <math.h>

#define S_LEN 2048
#define HIDD  2048
#define NHEAD 16
#define HD    128

// Tiled plane layout for all GEMM operands: plane = [rt][kt][128][32] bf16,
// tile = 8 KB contiguous. rt = row/128 (16 tiles), kt = k/32 (64 tiles).
#define TILE_SH 4096   // shorts per tile

typedef __attribute__((ext_vector_type(8))) short short8;
typedef __attribute__((ext_vector_type(4))) float float4v;
typedef unsigned short ushort_t;

static __device__ __forceinline__ ushort_t f2bf(float f) {
    unsigned int u = __float_as_uint(f);
    u += 0x7fff + ((u >> 16) & 1);
    return (ushort_t)(u >> 16);
}
static __device__ __forceinline__ float bf2f(ushort_t s) {
    return __uint_as_float(((unsigned int)s) << 16);
}
__device__ __forceinline__ float silu_f(float x) { return x / (1.f + expf(-x)); }

__device__ __forceinline__ void gl_lds16(const ushort_t* g, short* l) {
    __builtin_amdgcn_global_load_lds((const __attribute__((address_space(1))) void*)g,
                                     (__attribute__((address_space(3))) void*)l, 16, 0, 0);
}

// fp32 row-major -> (hi, lo) TILED bf16 planes
__global__ __launch_bounds__(256)
void split_kernel(const float* __restrict__ in, ushort_t* __restrict__ hi,
                  ushort_t* __restrict__ lo, int n4)
{
    const int i = blockIdx.x * 256 + threadIdx.x;
    if (i >= n4) return;
    const float4 v = ((const float4*)in)[i];
    ushort4 h, l;
    h.x = f2bf(v.x); l.x = f2bf(v.x - bf2f(h.x));
    h.y = f2bf(v.y); l.y = f2bf(v.y - bf2f(h.y));
    h.z = f2bf(v.z); l.z = f2bf(v.z - bf2f(h.z));
    h.w = f2bf(v.w); l.w = f2bf(v.w - bf2f(h.w));
    const int row = i >> 9, c4 = (i & 511) * 4;      // 512 float4 per 2048-row
    const size_t off = ((size_t)((row >> 7) * 64 + (c4 >> 5))) * TILE_SH
                     + (row & 127) * 32 + (c4 & 31);
    *(ushort4*)&hi[off] = h;
    *(ushort4*)&lo[off] = l;
}

// out += p0 + p1 + p2 (final reduction for MODE-1 split-K=4; p strided by n4 float4s)
__global__ __launch_bounds__(256)
void addp_kernel(float* __restrict__ out, const float* __restrict__ p, int n4)
{
    const int i = blockIdx.x * 256 + threadIdx.x;
    if (i >= n4) return;
    float4 a = ((const float4*)out)[i];
    const float4 b0 = ((const float4*)p)[i];
    const float4 b1 = ((const float4*)p)[i + n4];
    const float4 b2 = ((const float4*)p)[i + 2 * n4];
    a.x += b0.x + b1.x + b2.x;
    a.y += b0.y + b1.y + b2.y;
    a.z += b0.z + b1.z + b2.z;
    a.w += b0.w + b1.w + b2.w;
    ((float4*)out)[i] = a;
}

// W (K x N f32) -> WT hi/lo (N x K bf16), TILED
__global__ __launch_bounds__(256)
void split_transpose(const float* __restrict__ W, ushort_t* __restrict__ Thi,
                     ushort_t* __restrict__ Tlo)
{
    __shared__ float t[64][65];
    const int k0 = blockIdx.y * 64, n0 = blockIdx.x * 64;
    const int tx = threadIdx.x & 15, ty = threadIdx.x >> 4;
    #pragma unroll
    for (int it = 0; it < 4; it++) {
        const int k = ty + it * 16;
        const float4 v = *(const float4*)&W[(size_t)(k0 + k) * HIDD + n0 + tx * 4];
        t[k][tx * 4 + 0] = v.x; t[k][tx * 4 + 1] = v.y;
        t[k][tx * 4 + 2] = v.z; t[k][tx * 4 + 3] = v.w;
    }
    __syncthreads();
    #pragma unroll
    for (int it = 0; it < 4; it++) {
        const int n = ty + it * 16;
        ushort4 h, l; float a;
        a = t[tx * 4 + 0][n]; h.x = f2bf(a); l.x = f2bf(a - bf2f(h.x));
        a = t[tx * 4 + 1][n]; h.y = f2bf(a); l.y = f2bf(a - bf2f(h.y));
        a = t[tx * 4 + 2][n]; h.z = f2bf(a); l.z = f2bf(a - bf2f(h.z));
        a = t[tx * 4 + 3][n]; h.w = f2bf(a); l.w = f2bf(a - bf2f(h.w));
        const int nn_ = n0 + n, kk_ = k0 + tx * 4;
        const size_t off = ((size_t)((nn_ >> 7) * 64 + (kk_ >> 5))) * TILE_SH
                         + (nn_ & 127) * 32 + (kk_ & 31);
        *(ushort4*)&Thi[off] = h;
        *(ushort4*)&Tlo[off] = l;
    }
}

// Split-bf16 MFMA GEMM, 128x256 block tile (two n-tiles share one A-tile), BK=32.
// Rationale (r4): both r2 (2-barrier, 56% MfmaUtil) and r3 (full dbuf, 51%)
// pin near the LDS-traffic ceiling (~0.5 KB LDS per MFMA at 128x128).
// 128x256 with 64x128 wave tiles halves LDS reads/MFMA (0.25 KB) and
// barriers/FLOP, and amortizes A staging over 2x compute.
// LDS = A single 16 KB | B dbuf 2x32 KB = 80 KB -> exactly 2 blocks/CU.
// Schedule per kt: issue B(kt+1) prefetch (waves 2,3) -> compute (1864 cyc,
// hides the ~900 cyc HBM B-latency) -> lgkmcnt(0)+barrier -> A-stage(kt+1)
// (waves 0,1; only this L2-hot ~300 cyc latency is exposed) -> per-wave
// vmcnt(0)+barrier -> flip. Never drains the B prefetch mid-flight.
// MODE 0: x @ [WqT|WkT|WvT|WgT]; q/k xpos -> bf16 hi/lo [h][s][d]; v -> transposed
//         bf16 hi/lo [h][d][s]; g -> fp32 [s][2048]. Grid 512 (32 np x 16 m).
// MODE 1: y tiled planes @ WoT -> fp32, split-K=4 (8 np x 16 m x 4 kh = 512):
//         kh=0 -> outC, kh>=1 -> partial plane gbuf+(kh-1)*PL; addp sums 3.
template<int MODE>
__global__ __launch_bounds__(256, 2)
void mfma_gemm(const ushort_t* __restrict__ Ahi, const ushort_t* __restrict__ Alo,
               const ushort_t* __restrict__ WT, const int* __restrict__ pos_ids,
               ushort_t* __restrict__ qhi, ushort_t* __restrict__ qlo,
               ushort_t* __restrict__ khi, ushort_t* __restrict__ klo,
               ushort_t* __restrict__ vThi, ushort_t* __restrict__ vTlo,
               float* __restrict__ gbuf, float* __restrict__ outC)
{
    __shared__ __align__(16) short sm[40960];   // A 16KB | B0 32KB | B1 32KB

    const int tid = threadIdx.x;
    const int w = tid >> 6, L = tid & 63;
    const int qd = L >> 4, lc = L & 15;
    const int lin = blockIdx.x;
    int n0, m0, kh = 0;
    if (MODE == 0) {   // XCD-stable n-pair groups: XCD (lin&7 heuristic) sees np 4j..4j+3
        n0 = (((lin & 7) << 2) + ((lin >> 3) & 3)) << 8;
        m0 = (lin >> 5) << 7;
    } else {
        n0 = (lin & 7) << 8;
        m0 = ((lin >> 3) & 15) << 7;
        kh = lin >> 7;
    }
    const size_t PL = (size_t)HIDD * HIDD;

    int sel, nn;
    const ushort_t *Bhi, *Blo;
    if (MODE == 0) {
        sel = n0 >> 11; nn = n0 & 2047;   // 256-wide pair never crosses a sel boundary
        Bhi = WT + (size_t)sel * 2 * PL; Blo = Bhi + PL;
    } else {
        sel = -1; nn = n0;
        Bhi = WT; Blo = WT + PL;
    }

    // wave w stages plane w: 0:Ahi 1:Alo 2:Bhi(2 tiles) 3:Blo(2 tiles)
    const ushort_t* pbase = (w == 0) ? Ahi : (w == 1) ? Alo : (w == 2) ? Bhi : Blo;
    const int rt = ((w < 2) ? m0 : nn) >> 7;
    const ushort_t* tb0 = pbase + (size_t)rt * 64 * TILE_SH + L * 8;
    // for w>=2 the second n-tile is at tb0 + 64*TILE_SH

    const int wm = (w & 1) * 64;     // wave m-half
    const int wnh = w >> 1;          // wave n-tile (0 or 1)
    int aoff[4], boff[8];
    #pragma unroll
    for (int i = 0; i < 4; i++) aoff[i] = (wm + i * 16 + lc) * 32 + qd * 8;
    #pragma unroll
    for (int jj = 0; jj < 8; jj++) boff[jj] = (jj * 16 + lc) * 32 + qd * 8;

    float4v acc[4][8];
    #pragma unroll
    for (int i = 0; i < 4; i++)
        #pragma unroll
        for (int jj = 0; jj < 8; jj++)
            #pragma unroll
            for (int r = 0; r < 4; r++) acc[i][jj][r] = 0.f;

    const int kt0 = (MODE == 1) ? kh * 16 : 0;
    const int kt1 = (MODE == 1) ? kt0 + 16 : 64;

    // prologue: stage A(kt0) and B(kt0)->B0
    {
        const ushort_t* g = tb0 + (size_t)kt0 * TILE_SH;
        if (w < 2) {
            short* d = sm + w * 4096;
            #pragma unroll
            for (int t = 0; t < 8; t++) gl_lds16(g + t * 512, d + t * 512);
        } else {
            short* d = sm + 8192 + (w - 2) * 8192;
            #pragma unroll
            for (int t = 0; t < 8; t++) gl_lds16(g + t * 512, d + t * 512);
            #pragma unroll
            for (int t = 0; t < 8; t++) gl_lds16(g + 64 * TILE_SH + t * 512, d + 4096 + t * 512);
        }
        asm volatile("s_waitcnt vmcnt(0)" ::: "memory");
        __builtin_amdgcn_s_barrier();
        __builtin_amdgcn_sched_barrier(0);
    }

    int cur = 0;
    for (int kt = kt0; kt < kt1; kt++) {
        // issue B(kt+1) prefetch into the other buffer (stays in flight across compute)
        if (w >= 2 && kt + 1 < kt1) {
            const ushort_t* g = tb0 + (size_t)(kt + 1) * TILE_SH;
            short* d = sm + 8192 + ((cur ^ 1) * 16384) + (w - 2) * 8192;
            #pragma unroll
            for (int t = 0; t < 8; t++) gl_lds16(g + t * 512, d + t * 512);
            #pragma unroll
            for (int t = 0; t < 8; t++) gl_lds16(g + 64 * TILE_SH + t * 512, d + 4096 + t * 512);
        }

        short8 ah[4], al[4];
        #pragma unroll
        for (int i = 0; i < 4; i++) {
            ah[i] = *(const short8*)(sm + aoff[i]);
            al[i] = *(const short8*)(sm + 4096 + aoff[i]);
        }
        const short* bb = sm + 8192 + cur * 16384 + wnh * 4096;
        #pragma unroll
        for (int jh = 0; jh < 2; jh++) {
            short8 bh[4], bl[4];
            #pragma unroll
            for (int j = 0; j < 4; j++) {
                bh[j] = *(const short8*)(bb + boff[jh * 4 + j]);
                bl[j] = *(const short8*)(bb + 8192 + boff[jh * 4 + j]);
            }
            #pragma unroll
            for (int i = 0; i < 4; i++)
                #pragma unroll
                for (int j = 0; j < 4; j++) {
                    acc[i][jh * 4 + j] = __builtin_amdgcn_mfma_f32_16x16x32_bf16(ah[i], bh[j], acc[i][jh * 4 + j], 0, 0, 0);
                    acc[i][jh * 4 + j] = __builtin_amdgcn_mfma_f32_16x16x32_bf16(al[i], bh[j], acc[i][jh * 4 + j], 0, 0, 0);
                    acc[i][jh * 4 + j] = __builtin_amdgcn_mfma_f32_16x16x32_bf16(ah[i], bl[j], acc[i][jh * 4 + j], 0, 0, 0);
                }
        }

        // barrier #1: all LDS reads of Abuf done (NO vmcnt drain -> B stays in flight)
        asm volatile("s_waitcnt lgkmcnt(0)" ::: "memory");
        __builtin_amdgcn_s_barrier();
        __builtin_amdgcn_sched_barrier(0);
        // A-stage(kt+1) into the single A buffer (L2-hot, short exposed latency)
        if (w < 2 && kt + 1 < kt1) {
            const ushort_t* g = tb0 + (size_t)(kt + 1) * TILE_SH;
            short* d = sm + w * 4096;
            #pragma unroll
            for (int t = 0; t < 8; t++) gl_lds16(g + t * 512, d + t * 512);
        }
        // barrier #2: per-wave drain (A-wave waits A; B-waves' loads long landed)
        asm volatile("s_waitcnt vmcnt(0)" ::: "memory");
        __builtin_amdgcn_s_barrier();
        __builtin_amdgcn_sched_barrier(0);
        cur ^= 1;
    }

    // ---- epilogue via LDS bounce: ob = [32][260] f32 (32 m-rows x 256 n-cols per i).
    float* ob = (float*)sm;
    const int mh = w & 1;
    const int headb = nn >> 7;    // the 256-wide pair = heads (headb, headb+1)

    // #pragma unroll REQUIRED (rule #20): runtime i would put acc in scratch.
    #pragma unroll
    for (int i = 0; i < 4; i++) {
        #pragma unroll
        for (int jj = 0; jj < 8; jj++)
            #pragma unroll
            for (int r = 0; r < 4; r++)
                ob[(mh * 16 + qd * 4 + r) * 260 + wnh * 128 + jj * 16 + lc] = acc[i][jj][r];
        __syncthreads();

        if (MODE == 1 || sel == 3) {
            float* dst = (MODE == 1) ? ((kh == 0) ? outC : gbuf + (size_t)(kh - 1) * PL)
                                     : gbuf;
            #pragma unroll
            for (int p = 0; p < 8; p++) {
                const int row = p * 4 + (tid >> 6);
                const int c = (tid & 63) * 4;
                const int grow = m0 + (row >> 4) * 64 + i * 16 + (row & 15);
                const float4 vv = *(const float4*)&ob[row * 260 + c];
                *(float4*)&dst[(size_t)grow * HIDD + nn + c] = vv;
            }
        } else if (sel == 2) {
            const int d = tid >> 1, hs = tid & 1;
            const int sbase = m0 + hs * 64 + i * 16;
            #pragma unroll
            for (int nh = 0; nh < 2; nh++) {
                short8 h0, h1, l0, l1;
                #pragma unroll
                for (int sp = 0; sp < 8; sp++) {
                    float a = ob[(hs * 16 + sp) * 260 + nh * 128 + d];
                    ushort_t hb = f2bf(a);
                    h0[sp] = (short)hb; l0[sp] = (short)f2bf(a - bf2f(hb));
                    a = ob[(hs * 16 + 8 + sp) * 260 + nh * 128 + d];
                    hb = f2bf(a);
                    h1[sp] = (short)hb; l1[sp] = (short)f2bf(a - bf2f(hb));
                }
                ushort_t* dh = vThi + ((size_t)(headb + nh) * HD + d) * S_LEN + sbase;
                ushort_t* dl = vTlo + ((size_t)(headb + nh) * HD + d) * S_LEN + sbase;
                *(short8*)dh = h0; *(short8*)(dh + 8) = h1;
                *(short8*)dl = l0; *(short8*)(dl + 8) = l1;
            }
        } else {
            const float sgn = (sel == 0) ? 1.f : -1.f;
            ushort_t* dhb = (sel == 0) ? qhi : khi;
            ushort_t* dlb = (sel == 0) ? qlo : klo;
            #pragma unroll
            for (int nh = 0; nh < 2; nh++) {
                const int head = headb + nh;
                #pragma unroll
                for (int p = 0; p < 2; p++) {
                    const int row = p * 16 + (tid >> 4);
                    const int c8 = (tid & 15) * 8;
                    const int grow = m0 + (row >> 4) * 64 + i * 16 + (row & 15);
                    const float pos = (float)pos_ids[grow];
                    const float pe = sgn * pos * (1.f / 512.f);
                    short8 hv, lv;
                    #pragma unroll
                    for (int pp = 0; pp < 4; pp++) {
                        const int d = c8 + pp * 2;
                        const float v0 = ob[row * 260 + nh * 128 + d];
                        const float v1 = ob[row * 260 + nh * 128 + d + 1];
                        const float invf = exp2f(-(float)d * (13.28771238f / 128.f));
                        float s, c_; sincosf(pos * invf, &s, &c_);
                        const float scl = exp2f(log2f(((float)d + 51.2f) * (1.f / 179.2f)) * pe);
                        const float e0 = (v0 * c_ - v1 * s) * scl;
                        const float e1 = (v1 * c_ + v0 * s) * scl;
                        const ushort_t h0 = f2bf(e0), h1 = f2bf(e1);
                        hv[pp * 2] = (short)h0;  hv[pp * 2 + 1] = (short)h1;
                        lv[pp * 2] = (short)f2bf(e0 - bf2f(h0));
                        lv[pp * 2 + 1] = (short)f2bf(e1 - bf2f(h1));
                    }
                    *(short8*)&dhb[((size_t)head * S_LEN + grow) * HD + c8] = hv;
                    *(short8*)&dlb[((size_t)head * S_LEN + grow) * HD + c8] = lv;
                }
            }
        }
        __syncthreads();
    }
}

// Retention: MFMA QK^T -> decay -> P relayout -> MFMA PV -> groupnorm + silu gate
// -> y hi/lo TILED planes.  Block: (head, 64 q-rows), 4 waves.
#define KROW 136
#define VROW 40
#define KH_  0
#define KL_  (32 * KROW)
#define VH_  (2 * 32 * KROW)
#define VL_  (VH_ + 128 * VROW)
#define PH_  (VH_ + 2 * 128 * VROW)
#define PLO_ (PH_ + 64 * VROW)
#define YH_  8704
#define YL_  (YH_ + 64 * KROW)
__global__ __launch_bounds__(256, 2)
void retention2(const ushort_t* __restrict__ qhi, const ushort_t* __restrict__ qlo,
                const ushort_t* __restrict__ khi, const ushort_t* __restrict__ klo,
                const ushort_t* __restrict__ vThi, const ushort_t* __restrict__ vTlo,
                const float* __restrict__ gbuf, const float* __restrict__ gnw,
                const float* __restrict__ gnb,
                ushort_t* __restrict__ yhi, ushort_t* __restrict__ ylo)
{
    __shared__ __align__(16) short sm[26112];

    const int h = blockIdx.y;
    const int qb = (gridDim.x - 1) - blockIdx.x;
    const int r0 = qb * 64;
    const int tid = threadIdx.x;
    const int w = tid >> 6, L = tid & 63;
    const int qd = L >> 4, lc = L & 15;

    const float e = -3.4657359f + (float)h * ((-6.2383246f + 3.4657359f) / 15.f);
    const float lg2g = logf(1.f - expf(e)) * 1.44269504f;

    short8 qfh[4], qfl[4];
    {
        const size_t qb0 = ((size_t)h * S_LEN + r0 + w * 16 + lc) * HD + qd * 8;
        #pragma unroll
        for (int ks = 0; ks < 4; ks++) {
            qfh[ks] = *(const short8*)(qhi + qb0 + ks * 32);
            qfl[ks] = *(const short8*)(qlo + qb0 + ks * 32);
        }
    }

    float4v osum[2][4];
    #pragma unroll
    for (int mt = 0; mt < 2; mt++)
        #pragma unroll
        for (int j = 0; j < 4; j++)
            #pragma unroll
            for (int r = 0; r < 4; r++) osum[mt][j][r] = 0.f;

    const int qh_ = w >> 1, vh_ = w & 1;
    const int nch = (r0 + 64) / 32;

    for (int ch = 0; ch < nch; ch++) {
        const int kg0 = ch * 32;
        #pragma unroll
        for (int t = 0; t < 4; t++) {
            const int c = t * 256 + tid;
            const int p = c >> 9, r = (c >> 4) & 31, qq = c & 15;
            const ushort_t* src = (p ? klo : khi) + ((size_t)h * S_LEN + kg0 + r) * HD + qq * 8;
            *(short8*)(sm + (p ? KL_ : KH_) + r * KROW + qq * 8) = *(const short8*)src;
        }
        #pragma unroll
        for (int t = 0; t < 4; t++) {
            const int c = t * 256 + tid;
            const int p = c >> 9, r = (c >> 2) & 127, qq = c & 3;
            const ushort_t* src = (p ? vTlo : vThi) + ((size_t)h * HD + r) * S_LEN + kg0 + qq * 8;
            *(short8*)(sm + (p ? VL_ : VH_) + r * VROW + qq * 8) = *(const short8*)src;
        }
        __syncthreads();

        float4v sacc[2];
        #pragma unroll
        for (int j = 0; j < 2; j++)
            #pragma unroll
            for (int r = 0; r < 4; r++) sacc[j][r] = 0.f;
        #pragma unroll
        for (int ks = 0; ks < 4; ks++) {
            #pragma unroll
            for (int j = 0; j < 2; j++) {
                const short8 bh = *(const short8*)(sm + KH_ + (j * 16 + lc) * KROW + ks * 32 + qd * 8);
                const short8 bl = *(const short8*)(sm + KL_ + (j * 16 + lc) * KROW + ks * 32 + qd * 8);
                sacc[j] = __builtin_amdgcn_mfma_f32_16x16x32_bf16(qfh[ks], bh, sacc[j], 0, 0, 0);
                sacc[j] = __builtin_amdgcn_mfma_f32_16x16x32_bf16(qfl[ks], bh, sacc[j], 0, 0, 0);
                sacc[j] = __builtin_amdgcn_mfma_f32_16x16x32_bf16(qfh[ks], bl, sacc[j], 0, 0, 0);
            }
        }
        #pragma unroll
        for (int j = 0; j < 2; j++)
            #pragma unroll
            for (int r = 0; r < 4; r++) {
                const int dq = (r0 + w * 16 + qd * 4 + r) - (kg0 + j * 16 + lc);
                const float p = (dq >= 0) ? sacc[j][r] * exp2f(lg2g * (float)dq) : 0.f;
                const ushort_t hb = f2bf(p);
                const int off = (w * 16 + qd * 4 + r) * VROW + j * 16 + lc;
                sm[PH_ + off]  = (short)hb;
                sm[PLO_ + off] = (short)f2bf(p - bf2f(hb));
            }
        __syncthreads();

        #pragma unroll
        for (int mt = 0; mt < 2; mt++) {
            const short8 pfh = *(const short8*)(sm + PH_  + (qh_ * 32 + mt * 16 + lc) * VROW + qd * 8);
            const short8 pfl = *(const short8*)(sm + PLO_ + (qh_ * 32 + mt * 16 + lc) * VROW + qd * 8);
            #pragma unroll
            for (int j = 0; j < 4; j++) {
                const short8 vfh = *(const short8*)(sm + VH_ + (vh_ * 64 + j * 16 + lc) * VROW + qd * 8);
                const short8 vfl = *(const short8*)(sm + VL_ + (vh_ * 64 + j * 16 + lc) * VROW + qd * 8);
                osum[mt][j] = __builtin_amdgcn_mfma_f32_16x16x32_bf16(pfh, vfh, osum[mt][j], 0, 0, 0);
                osum[mt][j] = __builtin_amdgcn_mfma_f32_16x16x32_bf16(pfl, vfh, osum[mt][j], 0, 0, 0);
                osum[mt][j] = __builtin_amdgcn_mfma_f32_16x16x32_bf16(pfh, vfl, osum[mt][j], 0, 0, 0);
            }
        }
        __syncthreads();
    }

    float* fr = (float*)sm;
    #pragma unroll
    for (int mt = 0; mt < 2; mt++)
        #pragma unroll
        for (int r = 0; r < 4; r++) {
            float s1 = 0.f, s2 = 0.f;
            #pragma unroll
            for (int j = 0; j < 4; j++) { const float v = osum[mt][j][r]; s1 += v; s2 += v * v; }
            const int row = qh_ * 32 + mt * 16 + qd * 4 + r;
            fr[row * 32 + vh_ * 16 + lc] = s1;
            fr[2048 + row * 32 + vh_ * 16 + lc] = s2;
        }
    __syncthreads();
    if (tid < 64) {
        float s1 = 0.f, s2 = 0.f;
        #pragma unroll
        for (int t = 0; t < 32; t++) { s1 += fr[tid * 32 + t]; s2 += fr[2048 + tid * 32 + t]; }
        const float mean = s1 * (1.f / 128.f);
        const float var  = s2 * (1.f / 128.f) - mean * mean;
        fr[4096 + tid] = mean;
        fr[4160 + tid] = 1.f / sqrtf(var + 1e-5f);
    }
    __syncthreads();

    #pragma unroll
    for (int mt = 0; mt < 2; mt++)
        #pragma unroll
        for (int r = 0; r < 4; r++) {
            const int row = qh_ * 32 + mt * 16 + qd * 4 + r;
            const float mean = fr[4096 + row], inv = fr[4160 + row];
            const int grow = r0 + row;
            #pragma unroll
            for (int j = 0; j < 4; j++) {
                const int col = vh_ * 64 + j * 16 + lc;
                const float gv = gbuf[(size_t)grow * HIDD + h * HD + col];
                const float o = ((osum[mt][j][r] - mean) * inv * gnw[h * HD + col]
                                 + gnb[h * HD + col]) * silu_f(gv);
                const ushort_t hb = f2bf(o);
                sm[YH_ + row * KROW + col] = (short)hb;
                sm[YL_ + row * KROW + col] = (short)f2bf(o - bf2f(hb));
            }
        }
    __syncthreads();
    {
        // y -> TILED planes: row = r0+r_, col = h*128 + (tid&3)*32 + c8*8
        const int r_ = tid >> 2, cs = (tid & 3) * 32;
        const int grow = r0 + r_;
        const size_t tb = ((size_t)((grow >> 7) * 64 + h * 4 + (tid & 3))) * TILE_SH
                        + (grow & 127) * 32;
        #pragma unroll
        for (int c8 = 0; c8 < 4; c8++) {
            *(short8*)(yhi + tb + c8 * 8) = *(const short8*)(sm + YH_ + r_ * KROW + cs + c8 * 8);
            *(short8*)(ylo + tb + c8 * 8) = *(const short8*)(sm + YL_ + r_ * KROW + cs + c8 * 8);
        }
    }
}

extern "C" void kernel_launch(void* const* d_in, const int* in_sizes, int n_in,
                              void* d_out, int out_size, void* d_ws, size_t ws_size,
                              hipStream_t stream) {
    const float* x   = (const float*)d_in[0];
    const int*   pid = (const int*)d_in[1];
    const float* W[5] = {(const float*)d_in[2], (const float*)d_in[3], (const float*)d_in[4],
                         (const float*)d_in[5], (const float*)d_in[6]};
    const float* gnw = (const float*)d_in[7];
    const float* gnb = (const float*)d_in[8];
    float* out = (float*)d_out;
    (void)in_sizes; (void)n_in; (void)out_size; (void)ws_size;

    const size_t PL = (size_t)HIDD * HIDD;

    ushort_t* wt   = (ushort_t*)d_ws;          // 10 tiled planes = 80 MiB
    ushort_t* xhi  = wt + 10 * PL;             // tiled
    ushort_t* xlo  = xhi + PL;
    ushort_t* qhi_ = xlo + PL;                 // row-major [h][s][d]
    ushort_t* qlo_ = qhi_ + PL;
    ushort_t* khi_ = qlo_ + PL;
    ushort_t* klo_ = khi_ + PL;
    ushort_t* vThi = klo_ + PL;                // row-major [h][d][s]
    ushort_t* vTlo = vThi + PL;
    float*    gbuf = (float*)(vTlo + PL);      // row-major fp32
    ushort_t* yhi  = (ushort_t*)(gbuf + PL);   // tiled
    ushort_t* ylo  = yhi + PL;
    // MODE-1 split-K partials: 3 contiguous fp32 planes over xhi..klo_
    // (xhi/xlo dead after mfma_gemm<0>, qhi..klo dead after retention2).
    float*    pb   = (float*)xhi;

    split_kernel<<<(int)(PL / 4 / 256), 256, 0, stream>>>(x, xhi, xlo, (int)(PL / 4));
    for (int m = 0; m < 5; m++)
        split_transpose<<<dim3(32, 32), 256, 0, stream>>>(W[m], wt + (size_t)m * 2 * PL,
                                                          wt + (size_t)m * 2 * PL + PL);

    mfma_gemm<0><<<512, 256, 0, stream>>>(xhi, xlo, wt, pid,
        qhi_, qlo_, khi_, klo_, vThi, vTlo, gbuf, nullptr);

    retention2<<<dim3(32, 16), 256, 0, stream>>>(qhi_, qlo_, khi_, klo_, vThi, vTlo,
        gbuf, gnw, gnb, yhi, ylo);

    mfma_gemm<1><<<512, 256, 0, stream>>>(yhi, ylo, wt + 8 * PL, pid,
        nullptr, nullptr, nullptr, nullptr, nullptr, nullptr, pb, out);

    addp_kernel<<<(int)(PL / 4 / 256), 256, 0, stream>>>(out, pb, (int)(PL / 4));
}

// Round 5
// 544.645 us; speedup vs baseline: 1.0634x; 1.0634x over previous
//
#include <hip/hip_runtime.h>
#include <math.h>

#define S_LEN 2048
#define HIDD  2048
#define NHEAD 16
#define HD    128

// Tiled plane layout for all GEMM operands: plane = [rt][kt][128][32] bf16,
// tile = 8 KB contiguous. rt = row/128 (16 tiles), kt = k/32 (64 tiles).
#define TILE_SH 4096   // shorts per tile

typedef __attribute__((ext_vector_type(8))) short short8;
typedef __attribute__((ext_vector_type(4))) float float4v;
typedef unsigned short ushort_t;

static __device__ __forceinline__ ushort_t f2bf(float f) {
    unsigned int u = __float_as_uint(f);
    u += 0x7fff + ((u >> 16) & 1);
    return (ushort_t)(u >> 16);
}
static __device__ __forceinline__ float bf2f(ushort_t s) {
    return __uint_as_float(((unsigned int)s) << 16);
}
__device__ __forceinline__ float silu_f(float x) { return x / (1.f + expf(-x)); }

__device__ __forceinline__ void gl_lds16(const ushort_t* g, short* l) {
    __builtin_amdgcn_global_load_lds((const __attribute__((address_space(1))) void*)g,
                                     (__attribute__((address_space(3))) void*)l, 16, 0, 0);
}

// fp32 row-major -> (hi, lo) TILED bf16 planes
__global__ __launch_bounds__(256)
void split_kernel(const float* __restrict__ in, ushort_t* __restrict__ hi,
                  ushort_t* __restrict__ lo, int n4)
{
    const int i = blockIdx.x * 256 + threadIdx.x;
    if (i >= n4) return;
    const float4 v = ((const float4*)in)[i];
    ushort4 h, l;
    h.x = f2bf(v.x); l.x = f2bf(v.x - bf2f(h.x));
    h.y = f2bf(v.y); l.y = f2bf(v.y - bf2f(h.y));
    h.z = f2bf(v.z); l.z = f2bf(v.z - bf2f(h.z));
    h.w = f2bf(v.w); l.w = f2bf(v.w - bf2f(h.w));
    const int row = i >> 9, c4 = (i & 511) * 4;      // 512 float4 per 2048-row
    const size_t off = ((size_t)((row >> 7) * 64 + (c4 >> 5))) * TILE_SH
                     + (row & 127) * 32 + (c4 & 31);
    *(ushort4*)&hi[off] = h;
    *(ushort4*)&lo[off] = l;
}

// out += p0 + p1 + p2 (final reduction for MODE-1 split-K=4; p strided by n4 float4s)
__global__ __launch_bounds__(256)
void addp_kernel(float* __restrict__ out, const float* __restrict__ p, int n4)
{
    const int i = blockIdx.x * 256 + threadIdx.x;
    if (i >= n4) return;
    float4 a = ((const float4*)out)[i];
    const float4 b0 = ((const float4*)p)[i];
    const float4 b1 = ((const float4*)p)[i + n4];
    const float4 b2 = ((const float4*)p)[i + 2 * n4];
    a.x += b0.x + b1.x + b2.x;
    a.y += b0.y + b1.y + b2.y;
    a.z += b0.z + b1.z + b2.z;
    a.w += b0.w + b1.w + b2.w;
    ((float4*)out)[i] = a;
}

// W (K x N f32) -> WT hi/lo (N x K bf16), TILED
__global__ __launch_bounds__(256)
void split_transpose(const float* __restrict__ W, ushort_t* __restrict__ Thi,
                     ushort_t* __restrict__ Tlo)
{
    __shared__ float t[64][65];
    const int k0 = blockIdx.y * 64, n0 = blockIdx.x * 64;
    const int tx = threadIdx.x & 15, ty = threadIdx.x >> 4;
    #pragma unroll
    for (int it = 0; it < 4; it++) {
        const int k = ty + it * 16;
        const float4 v = *(const float4*)&W[(size_t)(k0 + k) * HIDD + n0 + tx * 4];
        t[k][tx * 4 + 0] = v.x; t[k][tx * 4 + 1] = v.y;
        t[k][tx * 4 + 2] = v.z; t[k][tx * 4 + 3] = v.w;
    }
    __syncthreads();
    #pragma unroll
    for (int it = 0; it < 4; it++) {
        const int n = ty + it * 16;
        ushort4 h, l; float a;
        a = t[tx * 4 + 0][n]; h.x = f2bf(a); l.x = f2bf(a - bf2f(h.x));
        a = t[tx * 4 + 1][n]; h.y = f2bf(a); l.y = f2bf(a - bf2f(h.y));
        a = t[tx * 4 + 2][n]; h.z = f2bf(a); l.z = f2bf(a - bf2f(h.z));
        a = t[tx * 4 + 3][n]; h.w = f2bf(a); l.w = f2bf(a - bf2f(h.w));
        const int nn_ = n0 + n, kk_ = k0 + tx * 4;
        const size_t off = ((size_t)((nn_ >> 7) * 64 + (kk_ >> 5))) * TILE_SH
                         + (nn_ & 127) * 32 + (kk_ & 31);
        *(ushort4*)&Thi[off] = h;
        *(ushort4*)&Tlo[off] = l;
    }
}

// Split-bf16 MFMA GEMM, 128x256 block tile, BK=32, 8 waves (512 threads),
// 64x64 wave tiles -> acc[4][4] = 64 regs/lane (r4's acc[4][8]=128 spilled:
// WRITE_SIZE 74->243 MB scratch writebacks; this reverts the footprint to the
// never-spilled r2/r3 level while keeping the 128x256 tile economics).
// LDS = A single 16 KB | B dbuf 2x32 KB = 80 KB -> 2 blocks/CU = 16 waves/CU
// (4/SIMD, 2x the TLP of r3/r4).
// Staging roles: waves 0-1 = Ahi/Alo tile; waves 2-5 = Bhi t0, Bhi t1,
// Blo t0, Blo t1; waves 6-7 compute-only.
// Schedule per kt: B-waves issue B(kt+1) into buf^1 -> compute from A + B[cur]
// -> lgkmcnt(0)+barrier -> A-waves stage A(kt+1) (L2-hot) -> vmcnt(0)+barrier
// -> flip. B prefetch latency hides under compute; only the short A-stage
// latency is exposed, covered by the co-resident block (4 waves/SIMD).
// MODE 0: x @ [WqT|WkT|WvT|WgT]; q/k xpos -> bf16 hi/lo [h][s][d]; v -> transposed
//         bf16 hi/lo [h][d][s]; g -> fp32 [s][2048]. Grid 512 (32 np x 16 m).
// MODE 1: y tiled planes @ WoT -> fp32, split-K=4 (8 np x 16 m x 4 kh = 512):
//         kh=0 -> outC, kh>=1 -> partial plane pbuf+(kh-1)*PL; addp sums 3.
template<int MODE>
__global__ __launch_bounds__(512, 4)
void mfma_gemm(const ushort_t* __restrict__ Ahi, const ushort_t* __restrict__ Alo,
               const ushort_t* __restrict__ WT, const int* __restrict__ pos_ids,
               ushort_t* __restrict__ qhi, ushort_t* __restrict__ qlo,
               ushort_t* __restrict__ khi, ushort_t* __restrict__ klo,
               ushort_t* __restrict__ vThi, ushort_t* __restrict__ vTlo,
               float* __restrict__ gbuf, float* __restrict__ outC)
{
    __shared__ __align__(16) short sm[40960];   // A 16KB | B0 32KB | B1 32KB

    const int tid = threadIdx.x;
    const int w = tid >> 6, L = tid & 63;
    const int qd = L >> 4, lc = L & 15;
    const int lin = blockIdx.x;
    int n0, m0, kh = 0;
    if (MODE == 0) {   // XCD-stable n-pair groups: XCD (lin&7 heuristic) sees np 4j..4j+3
        n0 = (((lin & 7) << 2) + ((lin >> 3) & 3)) << 8;
        m0 = (lin >> 5) << 7;
    } else {
        n0 = (lin & 7) << 8;
        m0 = ((lin >> 3) & 15) << 7;
        kh = lin >> 7;
    }
    const size_t PL = (size_t)HIDD * HIDD;

    int sel, nn;
    const ushort_t *Bhi, *Blo;
    if (MODE == 0) {
        sel = n0 >> 11; nn = n0 & 2047;   // 256-wide pair never crosses a sel boundary
        Bhi = WT + (size_t)sel * 2 * PL; Blo = Bhi + PL;
    } else {
        sel = -1; nn = n0;
        Bhi = WT; Blo = WT + PL;
    }

    // staging role: w0 Ahi, w1 Alo, w2 Bhi-t0, w3 Bhi-t1, w4 Blo-t0, w5 Blo-t1
    const ushort_t* pbase = (w == 0) ? Ahi : (w == 1) ? Alo : (w < 4) ? Bhi : Blo;
    const int rt = (w < 2) ? (m0 >> 7) : ((nn >> 7) + ((w - 2) & 1));
    const ushort_t* tb0 = pbase + (size_t)rt * 64 * TILE_SH + L * 8;

    // compute role: wave tile = rows wm..wm+63, cols ns*64..ns*64+63
    const int wm = (w & 1) * 64;
    const int ns = w >> 1;              // 0..3
    const int bt = ns >> 1;             // B n-tile 0/1
    const int br = (ns & 1) * 64;       // row base within B tile
    int aoff[4], boff[4];
    #pragma unroll
    for (int i = 0; i < 4; i++) aoff[i] = (wm + i * 16 + lc) * 32 + qd * 8;
    #pragma unroll
    for (int j = 0; j < 4; j++) boff[j] = bt * 4096 + (br + j * 16 + lc) * 32 + qd * 8;

    float4v acc[4][4];
    #pragma unroll
    for (int i = 0; i < 4; i++)
        #pragma unroll
        for (int j = 0; j < 4; j++)
            #pragma unroll
            for (int r = 0; r < 4; r++) acc[i][j][r] = 0.f;

    const int kt0 = (MODE == 1) ? kh * 16 : 0;
    const int kt1 = (MODE == 1) ? kt0 + 16 : 64;

    // prologue: stage A(kt0) and B(kt0)->buf0
    {
        const ushort_t* g = tb0 + (size_t)kt0 * TILE_SH;
        if (w < 2) {
            short* d = sm + w * 4096;
            #pragma unroll
            for (int t = 0; t < 8; t++) gl_lds16(g + t * 512, d + t * 512);
        } else if (w < 6) {
            short* d = sm + 8192 + (w - 2) * 4096;
            #pragma unroll
            for (int t = 0; t < 8; t++) gl_lds16(g + t * 512, d + t * 512);
        }
        asm volatile("s_waitcnt vmcnt(0)" ::: "memory");
        __builtin_amdgcn_s_barrier();
        __builtin_amdgcn_sched_barrier(0);
    }

    int cur = 0;
    for (int kt = kt0; kt < kt1; kt++) {
        // B prefetch for kt+1 into the other buffer (in flight across compute)
        if (w >= 2 && w < 6 && kt + 1 < kt1) {
            const ushort_t* g = tb0 + (size_t)(kt + 1) * TILE_SH;
            short* d = sm + 8192 + (cur ^ 1) * 16384 + (w - 2) * 4096;
            #pragma unroll
            for (int t = 0; t < 8; t++) gl_lds16(g + t * 512, d + t * 512);
        }

        short8 ah[4], al[4], bh[4], bl[4];
        const short* bb = sm + 8192 + cur * 16384;
        #pragma unroll
        for (int i = 0; i < 4; i++) {
            ah[i] = *(const short8*)(sm + aoff[i]);
            al[i] = *(const short8*)(sm + 4096 + aoff[i]);
        }
        #pragma unroll
        for (int j = 0; j < 4; j++) {
            bh[j] = *(const short8*)(bb + boff[j]);
            bl[j] = *(const short8*)(bb + 8192 + boff[j]);
        }
        #pragma unroll
        for (int i = 0; i < 4; i++)
            #pragma unroll
            for (int j = 0; j < 4; j++) {
                acc[i][j] = __builtin_amdgcn_mfma_f32_16x16x32_bf16(ah[i], bh[j], acc[i][j], 0, 0, 0);
                acc[i][j] = __builtin_amdgcn_mfma_f32_16x16x32_bf16(al[i], bh[j], acc[i][j], 0, 0, 0);
                acc[i][j] = __builtin_amdgcn_mfma_f32_16x16x32_bf16(ah[i], bl[j], acc[i][j], 0, 0, 0);
            }

        // barrier #1: LDS reads of A done; B prefetch stays in flight
        asm volatile("s_waitcnt lgkmcnt(0)" ::: "memory");
        __builtin_amdgcn_s_barrier();
        __builtin_amdgcn_sched_barrier(0);
        // A-stage(kt+1) into the single A buffer (L2-hot, short exposed latency)
        if (w < 2 && kt + 1 < kt1) {
            const ushort_t* g = tb0 + (size_t)(kt + 1) * TILE_SH;
            short* d = sm + w * 4096;
            #pragma unroll
            for (int t = 0; t < 8; t++) gl_lds16(g + t * 512, d + t * 512);
        }
        // barrier #2: per-wave drain (A-wave waits A; B-waves' prefetch landed
        // under the compute phase + co-resident block)
        asm volatile("s_waitcnt vmcnt(0)" ::: "memory");
        __builtin_amdgcn_s_barrier();
        __builtin_amdgcn_sched_barrier(0);
        cur ^= 1;
    }

    // ---- epilogue via LDS bounce: ob = [32][260] f32 (32 m-rows x 256 n-cols per i).
    float* ob = (float*)sm;
    const int mh = w & 1;
    const int headb = nn >> 7;    // the 256-wide pair = heads (headb, headb+1)

    // #pragma unroll REQUIRED (rule #20): runtime i would put acc in scratch.
    #pragma unroll
    for (int i = 0; i < 4; i++) {
        #pragma unroll
        for (int j = 0; j < 4; j++)
            #pragma unroll
            for (int r = 0; r < 4; r++)
                ob[(mh * 16 + qd * 4 + r) * 260 + ns * 64 + j * 16 + lc] = acc[i][j][r];
        __syncthreads();

        if (MODE == 1 || sel == 3) {
            float* dst = (MODE == 1) ? ((kh == 0) ? outC : gbuf + (size_t)(kh - 1) * PL)
                                     : gbuf;
            #pragma unroll
            for (int p = 0; p < 4; p++) {
                const int row = p * 8 + (tid >> 6);
                const int c = (tid & 63) * 4;
                const int grow = m0 + (row >> 4) * 64 + i * 16 + (row & 15);
                const float4 vv = *(const float4*)&ob[row * 260 + c];
                *(float4*)&dst[(size_t)grow * HIDD + nn + c] = vv;
            }
        } else if (sel == 2) {
            const int nh = tid >> 8, rem = tid & 255;
            const int d = rem >> 1, hs = rem & 1;
            const int sbase = m0 + hs * 64 + i * 16;
            short8 h0, h1, l0, l1;
            #pragma unroll
            for (int sp = 0; sp < 8; sp++) {
                float a = ob[(hs * 16 + sp) * 260 + nh * 128 + d];
                ushort_t hb = f2bf(a);
                h0[sp] = (short)hb; l0[sp] = (short)f2bf(a - bf2f(hb));
                a = ob[(hs * 16 + 8 + sp) * 260 + nh * 128 + d];
                hb = f2bf(a);
                h1[sp] = (short)hb; l1[sp] = (short)f2bf(a - bf2f(hb));
            }
            ushort_t* dh = vThi + ((size_t)(headb + nh) * HD + d) * S_LEN + sbase;
            ushort_t* dl = vTlo + ((size_t)(headb + nh) * HD + d) * S_LEN + sbase;
            *(short8*)dh = h0; *(short8*)(dh + 8) = h1;
            *(short8*)dl = l0; *(short8*)(dl + 8) = l1;
        } else {
            const float sgn = (sel == 0) ? 1.f : -1.f;
            ushort_t* dhb = (sel == 0) ? qhi : khi;
            ushort_t* dlb = (sel == 0) ? qlo : klo;
            const int nh = tid >> 8, rem = tid & 255;
            const int head = headb + nh;
            #pragma unroll
            for (int p = 0; p < 2; p++) {
                const int row = p * 16 + (rem >> 4);
                const int c8 = (rem & 15) * 8;
                const int grow = m0 + (row >> 4) * 64 + i * 16 + (row & 15);
                const float pos = (float)pos_ids[grow];
                const float pe = sgn * pos * (1.f / 512.f);
                short8 hv, lv;
                #pragma unroll
                for (int pp = 0; pp < 4; pp++) {
                    const int d = c8 + pp * 2;
                    const float v0 = ob[row * 260 + nh * 128 + d];
                    const float v1 = ob[row * 260 + nh * 128 + d + 1];
                    const float invf = exp2f(-(float)d * (13.28771238f / 128.f));
                    float s, c_; sincosf(pos * invf, &s, &c_);
                    const float scl = exp2f(log2f(((float)d + 51.2f) * (1.f / 179.2f)) * pe);
                    const float e0 = (v0 * c_ - v1 * s) * scl;
                    const float e1 = (v1 * c_ + v0 * s) * scl;
                    const ushort_t h0 = f2bf(e0), h1 = f2bf(e1);
                    hv[pp * 2] = (short)h0;  hv[pp * 2 + 1] = (short)h1;
                    lv[pp * 2] = (short)f2bf(e0 - bf2f(h0));
                    lv[pp * 2 + 1] = (short)f2bf(e1 - bf2f(h1));
                }
                *(short8*)&dhb[((size_t)head * S_LEN + grow) * HD + c8] = hv;
                *(short8*)&dlb[((size_t)head * S_LEN + grow) * HD + c8] = lv;
            }
        }
        __syncthreads();
    }
}

// Retention: MFMA QK^T -> decay -> P relayout -> MFMA PV -> groupnorm + silu gate
// -> y hi/lo TILED planes.  Block: (head, 64 q-rows), 4 waves.
#define KROW 136
#define VROW 40
#define KH_  0
#define KL_  (32 * KROW)
#define VH_  (2 * 32 * KROW)
#define VL_  (VH_ + 128 * VROW)
#define PH_  (VH_ + 2 * 128 * VROW)
#define PLO_ (PH_ + 64 * VROW)
#define YH_  8704
#define YL_  (YH_ + 64 * KROW)
__global__ __launch_bounds__(256, 2)
void retention2(const ushort_t* __restrict__ qhi, const ushort_t* __restrict__ qlo,
                const ushort_t* __restrict__ khi, const ushort_t* __restrict__ klo,
                const ushort_t* __restrict__ vThi, const ushort_t* __restrict__ vTlo,
                const float* __restrict__ gbuf, const float* __restrict__ gnw,
                const float* __restrict__ gnb,
                ushort_t* __restrict__ yhi, ushort_t* __restrict__ ylo)
{
    __shared__ __align__(16) short sm[26112];

    const int h = blockIdx.y;
    const int qb = (gridDim.x - 1) - blockIdx.x;
    const int r0 = qb * 64;
    const int tid = threadIdx.x;
    const int w = tid >> 6, L = tid & 63;
    const int qd = L >> 4, lc = L & 15;

    const float e = -3.4657359f + (float)h * ((-6.2383246f + 3.4657359f) / 15.f);
    const float lg2g = logf(1.f - expf(e)) * 1.44269504f;

    short8 qfh[4], qfl[4];
    {
        const size_t qb0 = ((size_t)h * S_LEN + r0 + w * 16 + lc) * HD + qd * 8;
        #pragma unroll
        for (int ks = 0; ks < 4; ks++) {
            qfh[ks] = *(const short8*)(qhi + qb0 + ks * 32);
            qfl[ks] = *(const short8*)(qlo + qb0 + ks * 32);
        }
    }

    float4v osum[2][4];
    #pragma unroll
    for (int mt = 0; mt < 2; mt++)
        #pragma unroll
        for (int j = 0; j < 4; j++)
            #pragma unroll
            for (int r = 0; r < 4; r++) osum[mt][j][r] = 0.f;

    const int qh_ = w >> 1, vh_ = w & 1;
    const int nch = (r0 + 64) / 32;

    for (int ch = 0; ch < nch; ch++) {
        const int kg0 = ch * 32;
        #pragma unroll
        for (int t = 0; t < 4; t++) {
            const int c = t * 256 + tid;
            const int p = c >> 9, r = (c >> 4) & 31, qq = c & 15;
            const ushort_t* src = (p ? klo : khi) + ((size_t)h * S_LEN + kg0 + r) * HD + qq * 8;
            *(short8*)(sm + (p ? KL_ : KH_) + r * KROW + qq * 8) = *(const short8*)src;
        }
        #pragma unroll
        for (int t = 0; t < 4; t++) {
            const int c = t * 256 + tid;
            const int p = c >> 9, r = (c >> 2) & 127, qq = c & 3;
            const ushort_t* src = (p ? vTlo : vThi) + ((size_t)h * HD + r) * S_LEN + kg0 + qq * 8;
            *(short8*)(sm + (p ? VL_ : VH_) + r * VROW + qq * 8) = *(const short8*)src;
        }
        __syncthreads();

        float4v sacc[2];
        #pragma unroll
        for (int j = 0; j < 2; j++)
            #pragma unroll
            for (int r = 0; r < 4; r++) sacc[j][r] = 0.f;
        #pragma unroll
        for (int ks = 0; ks < 4; ks++) {
            #pragma unroll
            for (int j = 0; j < 2; j++) {
                const short8 bh = *(const short8*)(sm + KH_ + (j * 16 + lc) * KROW + ks * 32 + qd * 8);
                const short8 bl = *(const short8*)(sm + KL_ + (j * 16 + lc) * KROW + ks * 32 + qd * 8);
                sacc[j] = __builtin_amdgcn_mfma_f32_16x16x32_bf16(qfh[ks], bh, sacc[j], 0, 0, 0);
                sacc[j] = __builtin_amdgcn_mfma_f32_16x16x32_bf16(qfl[ks], bh, sacc[j], 0, 0, 0);
                sacc[j] = __builtin_amdgcn_mfma_f32_16x16x32_bf16(qfh[ks], bl, sacc[j], 0, 0, 0);
            }
        }
        #pragma unroll
        for (int j = 0; j < 2; j++)
            #pragma unroll
            for (int r = 0; r < 4; r++) {
                const int dq = (r0 + w * 16 + qd * 4 + r) - (kg0 + j * 16 + lc);
                const float p = (dq >= 0) ? sacc[j][r] * exp2f(lg2g * (float)dq) : 0.f;
                const ushort_t hb = f2bf(p);
                const int off = (w * 16 + qd * 4 + r) * VROW + j * 16 + lc;
                sm[PH_ + off]  = (short)hb;
                sm[PLO_ + off] = (short)f2bf(p - bf2f(hb));
            }
        __syncthreads();

        #pragma unroll
        for (int mt = 0; mt < 2; mt++) {
            const short8 pfh = *(const short8*)(sm + PH_  + (qh_ * 32 + mt * 16 + lc) * VROW + qd * 8);
            const short8 pfl = *(const short8*)(sm + PLO_ + (qh_ * 32 + mt * 16 + lc) * VROW + qd * 8);
            #pragma unroll
            for (int j = 0; j < 4; j++) {
                const short8 vfh = *(const short8*)(sm + VH_ + (vh_ * 64 + j * 16 + lc) * VROW + qd * 8);
                const short8 vfl = *(const short8*)(sm + VL_ + (vh_ * 64 + j * 16 + lc) * VROW + qd * 8);
                osum[mt][j] = __builtin_amdgcn_mfma_f32_16x16x32_bf16(pfh, vfh, osum[mt][j], 0, 0, 0);
                osum[mt][j] = __builtin_amdgcn_mfma_f32_16x16x32_bf16(pfl, vfh, osum[mt][j], 0, 0, 0);
                osum[mt][j] = __builtin_amdgcn_mfma_f32_16x16x32_bf16(pfh, vfl, osum[mt][j], 0, 0, 0);
            }
        }
        __syncthreads();
    }

    float* fr = (float*)sm;
    #pragma unroll
    for (int mt = 0; mt < 2; mt++)
        #pragma unroll
        for (int r = 0; r < 4; r++) {
            float s1 = 0.f, s2 = 0.f;
            #pragma unroll
            for (int j = 0; j < 4; j++) { const float v = osum[mt][j][r]; s1 += v; s2 += v * v; }
            const int row = qh_ * 32 + mt * 16 + qd * 4 + r;
            fr[row * 32 + vh_ * 16 + lc] = s1;
            fr[2048 + row * 32 + vh_ * 16 + lc] = s2;
        }
    __syncthreads();
    if (tid < 64) {
        float s1 = 0.f, s2 = 0.f;
        #pragma unroll
        for (int t = 0; t < 32; t++) { s1 += fr[tid * 32 + t]; s2 += fr[2048 + tid * 32 + t]; }
        const float mean = s1 * (1.f / 128.f);
        const float var  = s2 * (1.f / 128.f) - mean * mean;
        fr[4096 + tid] = mean;
        fr[4160 + tid] = 1.f / sqrtf(var + 1e-5f);
    }
    __syncthreads();

    #pragma unroll
    for (int mt = 0; mt < 2; mt++)
        #pragma unroll
        for (int r = 0; r < 4; r++) {
            const int row = qh_ * 32 + mt * 16 + qd * 4 + r;
            const float mean = fr[4096 + row], inv = fr[4160 + row];
            const int grow = r0 + row;
            #pragma unroll
            for (int j = 0; j < 4; j++) {
                const int col = vh_ * 64 + j * 16 + lc;
                const float gv = gbuf[(size_t)grow * HIDD + h * HD + col];
                const float o = ((osum[mt][j][r] - mean) * inv * gnw[h * HD + col]
                                 + gnb[h * HD + col]) * silu_f(gv);
                const ushort_t hb = f2bf(o);
                sm[YH_ + row * KROW + col] = (short)hb;
                sm[YL_ + row * KROW + col] = (short)f2bf(o - bf2f(hb));
            }
        }
    __syncthreads();
    {
        // y -> TILED planes: row = r0+r_, col = h*128 + (tid&3)*32 + c8*8
        const int r_ = tid >> 2, cs = (tid & 3) * 32;
        const int grow = r0 + r_;
        const size_t tb = ((size_t)((grow >> 7) * 64 + h * 4 + (tid & 3))) * TILE_SH
                        + (grow & 127) * 32;
        #pragma unroll
        for (int c8 = 0; c8 < 4; c8++) {
            *(short8*)(yhi + tb + c8 * 8) = *(const short8*)(sm + YH_ + r_ * KROW + cs + c8 * 8);
            *(short8*)(ylo + tb + c8 * 8) = *(const short8*)(sm + YL_ + r_ * KROW + cs + c8 * 8);
        }
    }
}

extern "C" void kernel_launch(void* const* d_in, const int* in_sizes, int n_in,
                              void* d_out, int out_size, void* d_ws, size_t ws_size,
                              hipStream_t stream) {
    const float* x   = (const float*)d_in[0];
    const int*   pid = (const int*)d_in[1];
    const float* W[5] = {(const float*)d_in[2], (const float*)d_in[3], (const float*)d_in[4],
                         (const float*)d_in[5], (const float*)d_in[6]};
    const float* gnw = (const float*)d_in[7];
    const float* gnb = (const float*)d_in[8];
    float* out = (float*)d_out;
    (void)in_sizes; (void)n_in; (void)out_size; (void)ws_size;

    const size_t PL = (size_t)HIDD * HIDD;

    ushort_t* wt   = (ushort_t*)d_ws;          // 10 tiled planes = 80 MiB
    ushort_t* xhi  = wt + 10 * PL;             // tiled
    ushort_t* xlo  = xhi + PL;
    ushort_t* qhi_ = xlo + PL;                 // row-major [h][s][d]
    ushort_t* qlo_ = qhi_ + PL;
    ushort_t* khi_ = qlo_ + PL;
    ushort_t* klo_ = khi_ + PL;
    ushort_t* vThi = klo_ + PL;                // row-major [h][d][s]
    ushort_t* vTlo = vThi + PL;
    float*    gbuf = (float*)(vTlo + PL);      // row-major fp32
    ushort_t* yhi  = (ushort_t*)(gbuf + PL);   // tiled
    ushort_t* ylo  = yhi + PL;
    // MODE-1 split-K partials: 3 contiguous fp32 planes over xhi..klo_
    // (xhi/xlo dead after mfma_gemm<0>, qhi..klo dead after retention2).
    float*    pb   = (float*)xhi;

    split_kernel<<<(int)(PL / 4 / 256), 256, 0, stream>>>(x, xhi, xlo, (int)(PL / 4));
    for (int m = 0; m < 5; m++)
        split_transpose<<<dim3(32, 32), 256, 0, stream>>>(W[m], wt + (size_t)m * 2 * PL,
                                                          wt + (size_t)m * 2 * PL + PL);

    mfma_gemm<0><<<512, 512, 0, stream>>>(xhi, xlo, wt, pid,
        qhi_, qlo_, khi_, klo_, vThi, vTlo, gbuf, nullptr);

    retention2<<<dim3(32, 16), 256, 0, stream>>>(qhi_, qlo_, khi_, klo_, vThi, vTlo,
        gbuf, gnw, gnb, yhi, ylo);

    mfma_gemm<1><<<512, 512, 0, stream>>>(yhi, ylo, wt + 8 * PL, pid,
        nullptr, nullptr, nullptr, nullptr, nullptr, nullptr, pb, out);

    addp_kernel<<<(int)(PL / 4 / 256), 256, 0, stream>>>(out, pb, (int)(PL / 4));
}